// Round 2
// baseline (827.730 us; speedup 1.0000x reference)
//
#include <hip/hip_runtime.h>

constexpr int cT  = 1024;
constexpr int cD  = 512;
constexpr int cDK = 64;
constexpr int cP  = 2047;

typedef __attribute__((ext_vector_type(8))) short short8;
typedef __attribute__((ext_vector_type(4))) float floatx4;

#define MFMA16(a,b,c) __builtin_amdgcn_mfma_f32_16x16x32_bf16((a),(b),(c),0,0,0)

__device__ __forceinline__ unsigned short f2bf(float f){
  union { float f; unsigned int u; } x; x.f = f;
  unsigned int r = x.u + 0x7fffu + ((x.u >> 16) & 1u);   // RNE
  return (unsigned short)(r >> 16);
}
__device__ __forceinline__ float bf2f(unsigned short h){
  union { unsigned int u; float f; } x; x.u = ((unsigned int)h) << 16;
  return x.f;
}
__device__ __forceinline__ short8 ld8(const unsigned short* p){
  return *(const short8*)p;
}
// LDS column swizzle: breaks the 1024-word row stride so phase-4 fragment
// reads hit <=4-way bank conflicts instead of 16-way.
__device__ __forceinline__ int SW(int i, int j){ return j ^ ((i & 3) << 3); }

// ---------------- LayerNorm + cast to bf16 (one block per 512-wide row) ----------------
__global__ void __launch_bounds__(256) ln_bf16_kernel(
    const float* __restrict__ x, const float* __restrict__ g,
    const float* __restrict__ b, unsigned short* __restrict__ y)
{
  __shared__ float red[8];
  const int r = blockIdx.x;
  const float2 v = ((const float2*)(x + (size_t)r * cD))[threadIdx.x];
  float s = v.x + v.y, sq = v.x * v.x + v.y * v.y;
  #pragma unroll
  for (int o = 32; o; o >>= 1){ s += __shfl_xor(s, o); sq += __shfl_xor(sq, o); }
  const int w = threadIdx.x >> 6;
  if ((threadIdx.x & 63) == 0){ red[w * 2] = s; red[w * 2 + 1] = sq; }
  __syncthreads();
  s  = red[0] + red[2] + red[4] + red[6];
  sq = red[1] + red[3] + red[5] + red[7];
  const float mu  = s * (1.0f / cD);
  const float var = sq * (1.0f / cD) - mu * mu;
  const float rs  = rsqrtf(var + 1e-5f);
  const int c = threadIdx.x * 2;
  const unsigned int o0 = f2bf((v.x - mu) * rs * g[c]     + b[c]);
  const unsigned int o1 = f2bf((v.y - mu) * rs * g[c + 1] + b[c + 1]);
  ((unsigned int*)(y + (size_t)r * cD))[threadIdx.x] = o0 | (o1 << 16);
}

// ---------------- f32 -> bf16 casts ----------------
struct Ptr5 { const float* p[5]; };
__global__ void __launch_bounds__(256) cast5_kernel(Ptr5 s, unsigned short* __restrict__ d){
  const int idx = blockIdx.x * 256 + threadIdx.x;          // 5 * 262144 total
  const int seg = idx >> 18, off = idx & 262143;
  d[idx] = f2bf(s.p[seg][off]);
}
__global__ void __launch_bounds__(256) cast1_kernel(const float* __restrict__ s,
    unsigned short* __restrict__ d, int n){
  const int idx = blockIdx.x * 256 + threadIdx.x;
  if (idx < n) d[idx] = f2bf(s[idx]);
}

// ---------------- GEMM: Y[r][o] = sum_k A[r][k] * W[o][k] ; K = N = 512 fixed ----------
// mode 0: outb[((b*8+h)*1024+t)*64+d] bf16  (b=r>>10, t=r&1023, h=o>>6, d=o&63)
// mode 1: outb[(h*2047+r)*64+d]      bf16
// mode 2: outf[r*512+o] = acc + residual[r*512+o]   (f32 final output)
__global__ void __launch_bounds__(256) gemm512_kernel(
    const unsigned short* __restrict__ A, const unsigned short* __restrict__ W,
    int M, int mode, unsigned short* __restrict__ outb, float* __restrict__ outf,
    const float* __restrict__ residual)
{
  const int n0 = blockIdx.x * 128, m0 = blockIdx.y * 128;
  const int wave = threadIdx.x >> 6, lane = threadIdx.x & 63;
  const int wr = wave >> 1, wc = wave & 1;
  const int l15 = lane & 15, lq = lane >> 4;
  const int mb = m0 + wr * 64, nb = n0 + wc * 64;
  floatx4 acc[4][4];
  #pragma unroll
  for (int i = 0; i < 4; i++)
    #pragma unroll
    for (int j = 0; j < 4; j++) acc[i][j] = (floatx4){0.f, 0.f, 0.f, 0.f};
  for (int k0 = 0; k0 < 512; k0 += 32){
    short8 af[4], bf[4];
    #pragma unroll
    for (int i = 0; i < 4; i++){
      int row = mb + i * 16 + l15; if (row >= M) row = M - 1;
      af[i] = ld8(A + (size_t)row * 512 + k0 + lq * 8);
      const int col = nb + i * 16 + l15;
      bf[i] = ld8(W + (size_t)col * 512 + k0 + lq * 8);
    }
    #pragma unroll
    for (int i = 0; i < 4; i++)
      #pragma unroll
      for (int j = 0; j < 4; j++)
        acc[i][j] = MFMA16(af[i], bf[j], acc[i][j]);
  }
  #pragma unroll
  for (int i = 0; i < 4; i++){
    #pragma unroll
    for (int j = 0; j < 4; j++){
      #pragma unroll
      for (int r = 0; r < 4; r++){
        const int row = mb + i * 16 + lq * 4 + r;
        const int col = nb + j * 16 + l15;
        if (row >= M) continue;
        const float val = acc[i][j][r];
        if (mode == 0){
          const int bb = row >> 10, t = row & 1023, h = col >> 6, d = col & 63;
          outb[(((size_t)(bb * 8 + h) * 1024 + t) << 6) + d] = f2bf(val);
        } else if (mode == 1){
          const int h = col >> 6, d = col & 63;
          outb[(((size_t)h * 2047 + row) << 6) + d] = f2bf(val);
        } else {
          const size_t idx = (size_t)row * 512 + col;
          outf[idx] = val + residual[idx];
        }
      }
    }
  }
}

// ---------------- V transpose: [BH,T,64] -> [BH,64,T] ----------------
__global__ void __launch_bounds__(256) transpose_v_kernel(
    const unsigned short* __restrict__ vh, unsigned short* __restrict__ vt)
{
  __shared__ unsigned short tile[64][65];
  const int bh = blockIdx.x, t0 = blockIdx.y * 64;
  const unsigned short* src = vh + ((size_t)bh * cT + t0) * cDK;
  #pragma unroll
  for (int i = 0; i < 16; i++){
    const int idx = threadIdx.x + i * 256;
    tile[idx >> 6][idx & 63] = src[idx];
  }
  __syncthreads();
  unsigned short* dst = vt + (size_t)bh * cDK * cT + t0;
  #pragma unroll
  for (int i = 0; i < 16; i++){
    const int idx = threadIdx.x + i * 256;
    const int d = idx >> 6, t = idx & 63;
    dst[(size_t)d * cT + t] = tile[t][d];
  }
}

// ---------------- per-key bias: out[row] = dot64(bias[h], X[row]) ----------------
__global__ void __launch_bounds__(256) dot_bias_kernel(
    const unsigned short* __restrict__ X, const float* __restrict__ bias,
    float* __restrict__ out, int rows, int hdiv)
{
  const int row = blockIdx.x * 4 + (threadIdx.x >> 6);
  const int lane = threadIdx.x & 63;
  if (row >= rows) return;
  const int h = (row / hdiv) & 7;
  float s = bf2f(X[(size_t)row * 64 + lane]) * bias[h * 64 + lane];
  #pragma unroll
  for (int o = 32; o; o >>= 1) s += __shfl_xor(s, o);
  if (lane == 0) out[row] = s;
}

// ---------------- fused relpos attention: block = (b,h, 16 q-rows) ----------------
// scores f32 in 64KB static LDS (swizzled, no pad); rel_shift = diagonal scatter.
__global__ void __launch_bounds__(256) attn_kernel(
    const unsigned short* __restrict__ qh, const unsigned short* __restrict__ kh,
    const unsigned short* __restrict__ vt, const unsigned short* __restrict__ pproj,
    const float* __restrict__ ubias, const float* __restrict__ vbias,
    const int* __restrict__ mask, float* __restrict__ attn_out,
    unsigned short* __restrict__ out_h)
{
  __shared__ float sc[16 * cT];    // exactly 64 KiB
  const int bh = blockIdx.x, b = bh >> 3, h = bh & 7;
  const int q0 = blockIdx.y * 16;
  const int wave = threadIdx.x >> 6, lane = threadIdx.x & 63;
  const int l15 = lane & 15, lq = lane >> 4;
  const unsigned short* Q  = qh + (size_t)bh * cT * cDK;
  const unsigned short* Kp = kh + (size_t)bh * cT * cDK;
  const unsigned short* Pt = pproj + (size_t)h * cP * cDK;

  // Q A-fragments (m = lane&15, k = quad*8+j), shared by QK and QP GEMMs
  short8 qf0 = ld8(Q + (size_t)(q0 + l15) * cDK + lq * 8);
  short8 qf1 = ld8(Q + (size_t)(q0 + l15) * cDK + 32 + lq * 8);

  // ---- phase 1: ac = Q K^T -> LDS ----
  for (int jt = wave; jt < 64; jt += 4){
    const short8 kf0 = ld8(Kp + (size_t)(jt * 16 + l15) * cDK + lq * 8);
    const short8 kf1 = ld8(Kp + (size_t)(jt * 16 + l15) * cDK + 32 + lq * 8);
    floatx4 acc = (floatx4){0.f, 0.f, 0.f, 0.f};
    acc = MFMA16(qf0, kf0, acc);
    acc = MFMA16(qf1, kf1, acc);
    #pragma unroll
    for (int r = 0; r < 4; r++){
      const int i = lq * 4 + r, j = jt * 16 + l15;
      sc[i * cT + SW(i, j)] = acc[r];
    }
  }
  __syncthreads();

  // ---- phase 2: bd window GEMM, diagonal scatter-add  j = c - 15 + i ----
  const int w0 = (cT - 1) - q0 - 15;   // in [0, 1008]
  for (int ct = wave; ct < 65; ct += 4){
    const int c = ct * 16 + l15;
    int prow = w0 + c; if (prow > cP - 1) prow = cP - 1;  // clamped rows -> j>=1024, dropped
    const short8 pf0 = ld8(Pt + (size_t)prow * cDK + lq * 8);
    const short8 pf1 = ld8(Pt + (size_t)prow * cDK + 32 + lq * 8);
    floatx4 acc = (floatx4){0.f, 0.f, 0.f, 0.f};
    acc = MFMA16(qf0, pf0, acc);
    acc = MFMA16(qf1, pf1, acc);
    #pragma unroll
    for (int r = 0; r < 4; r++){
      const int i = lq * 4 + r;
      const int j = c - 15 + i;
      if (j >= 0 && j < cT) sc[i * cT + SW(i, j)] += acc[r];
    }
  }
  __syncthreads();

  // ---- phase 3: masked softmax; write f32 attn; keep NORMALIZED p in LDS ----
  const float* ub = ubias + (size_t)bh * cT;
  const float* vb = vbias + (size_t)h * cP;
  for (int r4 = 0; r4 < 4; r4++){
    const int i = wave * 4 + r4;
    const int qrow = q0 + i;
    const int* mrow = mask + ((size_t)b * cT + qrow) * cT;
    float vals[16];
    float mx = -INFINITY;
    #pragma unroll
    for (int ii = 0; ii < 16; ii++){
      const int j = lane + ii * 64;
      float s = sc[i * cT + SW(i, j)] + ub[j] + vb[j + (cT - 1) - qrow];
      s *= 0.125f;
      if (mrow[j] == 0) s = -INFINITY;
      vals[ii] = s;
      mx = fmaxf(mx, s);
    }
    #pragma unroll
    for (int o = 32; o; o >>= 1) mx = fmaxf(mx, __shfl_xor(mx, o));
    float sum = 0.f;
    #pragma unroll
    for (int ii = 0; ii < 16; ii++){
      const float e = (vals[ii] == -INFINITY) ? 0.f : __expf(vals[ii] - mx);
      vals[ii] = e; sum += e;
    }
    #pragma unroll
    for (int o = 32; o; o >>= 1) sum += __shfl_xor(sum, o);
    const float ri = sum > 0.f ? 1.f / sum : 0.f;
    float* arow = attn_out + ((size_t)bh * cT + qrow) * cT;
    #pragma unroll
    for (int ii = 0; ii < 16; ii++){
      const int j = lane + ii * 64;
      const float p = vals[ii] * ri;
      arow[j] = p;                    // coalesced f32 store
      sc[i * cT + SW(i, j)] = p;      // normalized prob for PV
    }
  }
  __syncthreads();

  // ---- phase 4: O = P V ; wave owns a 16-wide d-slice ----
  const unsigned short* V = vt + (size_t)bh * cDK * cT;
  const int d0 = wave * 16;
  floatx4 acc = (floatx4){0.f, 0.f, 0.f, 0.f};
  for (int ks = 0; ks < 32; ks++){
    const int j0 = ks * 32;
    const short8 vf = ld8(V + (size_t)(d0 + l15) * cT + j0 + lq * 8);
    short8 af;
    #pragma unroll
    for (int jj = 0; jj < 8; jj++){
      const int j = j0 + lq * 8 + jj;
      af[jj] = (short)f2bf(sc[l15 * cT + SW(l15, j)]);
    }
    acc = MFMA16(af, vf, acc);
  }
  #pragma unroll
  for (int r = 0; r < 4; r++){
    const int i = lq * 4 + r;
    out_h[((size_t)b * cT + q0 + i) * cD + h * cDK + d0 + l15] = f2bf(acc[r]);
  }
}

// ---------------- host launcher ----------------
extern "C" void kernel_launch(void* const* d_in, const int* in_sizes, int n_in,
                              void* d_out, int out_size, void* d_ws, size_t ws_size,
                              hipStream_t stream)
{
  const float* q    = (const float*)d_in[0];
  const float* k    = (const float*)d_in[1];
  const float* v    = (const float*)d_in[2];
  const float* pe   = (const float*)d_in[3];
  const int*   mask = (const int*)d_in[4];
  const float* lnqg = (const float*)d_in[5];
  const float* lnqb = (const float*)d_in[6];
  const float* lnkg = (const float*)d_in[7];
  const float* lnkb = (const float*)d_in[8];
  const float* lnvg = (const float*)d_in[9];
  const float* lnvb = (const float*)d_in[10];
  const float* wq   = (const float*)d_in[11];
  const float* wk   = (const float*)d_in[12];
  const float* wv   = (const float*)d_in[13];
  const float* wpos = (const float*)d_in[14];
  const float* wfc  = (const float*)d_in[15];
  const float* pbu  = (const float*)d_in[16];
  const float* pbv  = (const float*)d_in[17];

  float* out_f  = (float*)d_out;                       // [8,1024,512] f32
  float* attn_f = out_f + (size_t)8 * 1024 * 512;      // [8,8,1024,1024] f32, 268 MB

  // --- scratch that dies before attn_kernel lives inside the attn output region ---
  unsigned char* scr = (unsigned char*)attn_f;
  size_t soff = 0;
  auto salloc = [&](size_t bytes){ void* p = scr + soff; soff += (bytes + 255) & ~(size_t)255; return p; };
  unsigned short* qn   = (unsigned short*)salloc((size_t)8192 * 512 * 2);
  unsigned short* kn   = (unsigned short*)salloc((size_t)8192 * 512 * 2);
  unsigned short* vn   = (unsigned short*)salloc((size_t)8192 * 512 * 2);
  unsigned short* vhb  = (unsigned short*)salloc((size_t)8192 * 512 * 2); // [B,H,T,64]
  unsigned short* pe_b = (unsigned short*)salloc((size_t)2047 * 512 * 2);

  // --- workspace: buffers live across / after attn_kernel (~39 MB) ---
  unsigned char* ws = (unsigned char*)d_ws;
  size_t off = 0;
  auto alloc = [&](size_t bytes){ void* p = ws + off; off += (bytes + 255) & ~(size_t)255; return p; };
  unsigned short* w5_b = (unsigned short*)alloc(5 * 512 * 512 * 2); // wq,wk,wv,wpos,wfc
  unsigned short* qhb  = (unsigned short*)alloc((size_t)8192 * 512 * 2); // [B,H,T,64]
  unsigned short* khb  = (unsigned short*)alloc((size_t)8192 * 512 * 2);
  unsigned short* vtb  = (unsigned short*)alloc((size_t)8192 * 512 * 2); // [B,H,64,T]
  unsigned short* ppb  = (unsigned short*)alloc((size_t)8 * 2047 * 64 * 2); // [H,P,64]
  float*          ub   = (float*)alloc((size_t)8 * 8 * 1024 * 4);  // [B,H,T]
  float*          vbias= (float*)alloc((size_t)8 * 2047 * 4);      // [H,P]
  unsigned short* ohb  = (unsigned short*)alloc((size_t)8192 * 512 * 2); // [B,T,512]
  (void)ws_size; (void)n_in; (void)in_sizes; (void)out_size;

  Ptr5 c5; c5.p[0] = wq; c5.p[1] = wk; c5.p[2] = wv; c5.p[3] = wpos; c5.p[4] = wfc;
  cast5_kernel<<<5120, 256, 0, stream>>>(c5, w5_b);
  cast1_kernel<<<4094, 256, 0, stream>>>(pe, pe_b, 2047 * 512);

  ln_bf16_kernel<<<8192, 256, 0, stream>>>(q, lnqg, lnqb, qn);
  ln_bf16_kernel<<<8192, 256, 0, stream>>>(k, lnkg, lnkb, kn);
  ln_bf16_kernel<<<8192, 256, 0, stream>>>(v, lnvg, lnvb, vn);

  const unsigned short* wq_b   = w5_b;
  const unsigned short* wk_b   = w5_b + 262144;
  const unsigned short* wv_b   = w5_b + 2 * 262144;
  const unsigned short* wpos_b = w5_b + 3 * 262144;
  const unsigned short* wfc_b  = w5_b + 4 * 262144;

  gemm512_kernel<<<dim3(4, 64), 256, 0, stream>>>(qn, wq_b,   8192, 0, qhb, nullptr, nullptr);
  gemm512_kernel<<<dim3(4, 64), 256, 0, stream>>>(kn, wk_b,   8192, 0, khb, nullptr, nullptr);
  gemm512_kernel<<<dim3(4, 64), 256, 0, stream>>>(vn, wv_b,   8192, 0, vhb, nullptr, nullptr);
  gemm512_kernel<<<dim3(4, 16), 256, 0, stream>>>(pe_b, wpos_b, 2047, 1, ppb, nullptr, nullptr);

  transpose_v_kernel<<<dim3(64, 16), 256, 0, stream>>>(vhb, vtb);

  dot_bias_kernel<<<16384, 256, 0, stream>>>(khb, pbu, ub, 65536, 1024);
  dot_bias_kernel<<<4094, 256, 0, stream>>>(ppb, pbv, vbias, 16376, 2047);

  // attn_kernel overwrites the entire attn region (scratch above is dead by now)
  attn_kernel<<<dim3(64, 64), 256, 0, stream>>>(qhb, khb, vtb, ppb, ub, vbias,
                                                mask, attn_f, ohb);

  gemm512_kernel<<<dim3(4, 64), 256, 0, stream>>>(ohb, wfc_b, 8192, 2, nullptr, out_f, q);
}

// Round 3
// 736.658 us; speedup vs baseline: 1.1236x; 1.1236x over previous
//
#include <hip/hip_runtime.h>

constexpr int cT  = 1024;
constexpr int cD  = 512;
constexpr int cDK = 64;
constexpr int cP  = 2047;
constexpr int PBS = 1040;   // bf16 prob-buffer row stride (pad 16 -> +8 banks/row)

typedef __attribute__((ext_vector_type(8))) short short8;
typedef __attribute__((ext_vector_type(4))) float floatx4;

#define MFMA16(a,b,c) __builtin_amdgcn_mfma_f32_16x16x32_bf16((a),(b),(c),0,0,0)
// swizzle keyed on i>>2 (varies across lanes within a store), not i&3 (constant)
#define SWZ(i,j) ((j) ^ ((((i) >> 2) & 3) << 3))

__device__ __forceinline__ unsigned short f2bf(float f){
  union { float f; unsigned int u; } x; x.f = f;
  unsigned int r = x.u + 0x7fffu + ((x.u >> 16) & 1u);   // RNE
  return (unsigned short)(r >> 16);
}
__device__ __forceinline__ float bf2f(unsigned short h){
  union { unsigned int u; float f; } x; x.u = ((unsigned int)h) << 16;
  return x.f;
}
__device__ __forceinline__ short8 ld8(const unsigned short* p){
  return *(const short8*)p;
}

// ---------------- LayerNorm x3 + cast to bf16 ----------------
struct LN3 { const float* x[3]; const float* g[3]; const float* b[3]; unsigned short* y[3]; };
__global__ void __launch_bounds__(256) ln3_kernel(LN3 a)
{
  __shared__ float red[8];
  const int z = blockIdx.y, r = blockIdx.x;
  const float* x = a.x[z]; const float* g = a.g[z]; const float* b = a.b[z];
  unsigned short* y = a.y[z];
  const float2 v = ((const float2*)(x + (size_t)r * cD))[threadIdx.x];
  float s = v.x + v.y, sq = v.x * v.x + v.y * v.y;
  #pragma unroll
  for (int o = 32; o; o >>= 1){ s += __shfl_xor(s, o); sq += __shfl_xor(sq, o); }
  const int w = threadIdx.x >> 6;
  if ((threadIdx.x & 63) == 0){ red[w * 2] = s; red[w * 2 + 1] = sq; }
  __syncthreads();
  s  = red[0] + red[2] + red[4] + red[6];
  sq = red[1] + red[3] + red[5] + red[7];
  const float mu  = s * (1.0f / cD);
  const float var = sq * (1.0f / cD) - mu * mu;
  const float rs  = rsqrtf(var + 1e-5f);
  const int c = threadIdx.x * 2;
  const unsigned int o0 = f2bf((v.x - mu) * rs * g[c]     + b[c]);
  const unsigned int o1 = f2bf((v.y - mu) * rs * g[c + 1] + b[c + 1]);
  ((unsigned int*)(y + (size_t)r * cD))[threadIdx.x] = o0 | (o1 << 16);
}

// ---------------- f32 -> bf16 casts ----------------
struct Ptr5 { const float* p[5]; };
__global__ void __launch_bounds__(256) cast5_kernel(Ptr5 s, unsigned short* __restrict__ d){
  const int idx = blockIdx.x * 256 + threadIdx.x;          // 5 * 262144 total
  const int seg = idx >> 18, off = idx & 262143;
  d[idx] = f2bf(s.p[seg][off]);
}
__global__ void __launch_bounds__(256) cast1_kernel(const float* __restrict__ s,
    unsigned short* __restrict__ d, int n){
  const int idx = blockIdx.x * 256 + threadIdx.x;
  if (idx < n) d[idx] = f2bf(s[idx]);
}

// ---------------- mask -> bitmask: bm[(b*T+t)*32 + w] bit (j&31) = mask!=0 ----------------
__global__ void __launch_bounds__(256) maskbits_kernel(
    const int* __restrict__ mask, unsigned int* __restrict__ bm)
{
  const int row = blockIdx.x * 4 + (threadIdx.x >> 6);
  const int lane = threadIdx.x & 63;
  #pragma unroll
  for (int ii = 0; ii < 16; ii++){
    const int m = mask[(size_t)row * cT + ii * 64 + lane];
    const unsigned long long bal = __ballot(m != 0);
    if (lane == 0)       bm[row * 32 + ii * 2]     = (unsigned int)bal;
    else if (lane == 32) bm[row * 32 + ii * 2 + 1] = (unsigned int)(bal >> 32);
  }
}

// ---------------- GEMM: Y[r][o] = scale * sum_k A[r][k] * W[o][k]; K=N=512 ------------
// fused==1: A/W/outb advance by blockIdx.z (QKV); scaleA applies to z==0 only.
// mode 0: outb[((b*8+h)*1024+t)*64+d] bf16 ; mode 1: outb[(h*2047+r)*64+d] bf16
// mode 2: outf[r*512+o] = acc + residual[r*512+o] (f32 final output)
__global__ void __launch_bounds__(256) gemm512_kernel(
    const unsigned short* __restrict__ A0, const unsigned short* __restrict__ W0,
    int M, int mode, float scaleA, unsigned short* __restrict__ outb,
    float* __restrict__ outf, const float* __restrict__ residual)
{
  const int z = blockIdx.z;
  const unsigned short* A = A0 + (size_t)z * 4194304;
  const unsigned short* W = W0 + (size_t)z * 262144;
  unsigned short* outz = outb ? outb + (size_t)z * 4194304 : outb;
  const float sA = (z == 0) ? scaleA : 1.0f;
  const int n0 = blockIdx.x * 128, m0 = blockIdx.y * 128;
  const int wave = threadIdx.x >> 6, lane = threadIdx.x & 63;
  const int wr = wave >> 1, wc = wave & 1;
  const int l15 = lane & 15, lq = lane >> 4;
  const int mb = m0 + wr * 64, nb = n0 + wc * 64;
  floatx4 acc[4][4];
  #pragma unroll
  for (int i = 0; i < 4; i++)
    #pragma unroll
    for (int j = 0; j < 4; j++) acc[i][j] = (floatx4){0.f, 0.f, 0.f, 0.f};
  for (int k0 = 0; k0 < 512; k0 += 32){
    short8 af[4], bf[4];
    #pragma unroll
    for (int i = 0; i < 4; i++){
      int row = mb + i * 16 + l15; if (row >= M) row = M - 1;
      af[i] = ld8(A + (size_t)row * 512 + k0 + lq * 8);
      const int col = nb + i * 16 + l15;
      bf[i] = ld8(W + (size_t)col * 512 + k0 + lq * 8);
    }
    #pragma unroll
    for (int i = 0; i < 4; i++)
      #pragma unroll
      for (int j = 0; j < 4; j++)
        acc[i][j] = MFMA16(af[i], bf[j], acc[i][j]);
  }
  #pragma unroll
  for (int i = 0; i < 4; i++){
    #pragma unroll
    for (int j = 0; j < 4; j++){
      #pragma unroll
      for (int r = 0; r < 4; r++){
        const int row = mb + i * 16 + lq * 4 + r;
        const int col = nb + j * 16 + l15;
        if (row >= M) continue;
        const float val = acc[i][j][r] * sA;
        if (mode == 0){
          const int bb = row >> 10, t = row & 1023, h = col >> 6, d = col & 63;
          outz[(((size_t)(bb * 8 + h) * 1024 + t) << 6) + d] = f2bf(val);
        } else if (mode == 1){
          const int h = col >> 6, d = col & 63;
          outz[(((size_t)h * 2047 + row) << 6) + d] = f2bf(val);
        } else {
          const size_t idx = (size_t)row * 512 + col;
          outf[idx] = val + residual[idx];
        }
      }
    }
  }
}

// ---------------- V transpose: [BH,T,64] -> [BH,64,T] ----------------
__global__ void __launch_bounds__(256) transpose_v_kernel(
    const unsigned short* __restrict__ vh, unsigned short* __restrict__ vt)
{
  __shared__ unsigned short tile[64][65];
  const int bh = blockIdx.x, t0 = blockIdx.y * 64;
  const unsigned short* src = vh + ((size_t)bh * cT + t0) * cDK;
  #pragma unroll
  for (int i = 0; i < 16; i++){
    const int idx = threadIdx.x + i * 256;
    tile[idx >> 6][idx & 63] = src[idx];
  }
  __syncthreads();
  unsigned short* dst = vt + (size_t)bh * cDK * cT + t0;
  #pragma unroll
  for (int i = 0; i < 16; i++){
    const int idx = threadIdx.x + i * 256;
    const int d = idx >> 6, t = idx & 63;
    dst[(size_t)d * cT + t] = tile[t][d];
  }
}

// ---------------- per-key bias: out[row] = scale * dot64(bias[h], X[row]) ----------------
__global__ void __launch_bounds__(256) dot_bias_kernel(
    const unsigned short* __restrict__ X, const float* __restrict__ bias,
    float* __restrict__ out, int rows, int hdiv, float scale)
{
  const int row = blockIdx.x * 4 + (threadIdx.x >> 6);
  const int lane = threadIdx.x & 63;
  if (row >= rows) return;
  const int h = (row / hdiv) & 7;
  float s = bf2f(X[(size_t)row * 64 + lane]) * bias[h * 64 + lane];
  #pragma unroll
  for (int o = 32; o; o >>= 1) s += __shfl_xor(s, o);
  if (lane == 0) out[row] = s * scale;
}

// ---------------- fused relpos attention: block = (b,h, 16 q-rows) ----------------
// scale (1/8) pre-folded into qh / ubias / vbias.
__global__ void __launch_bounds__(256) attn_kernel(
    const unsigned short* __restrict__ qh, const unsigned short* __restrict__ kh,
    const unsigned short* __restrict__ vt, const unsigned short* __restrict__ pproj,
    const float* __restrict__ ubias, const float* __restrict__ vbias,
    const unsigned int* __restrict__ bm, float* __restrict__ attn_out,
    unsigned short* __restrict__ out_h)
{
  __shared__ float sc[16 * cT];                 // 64 KiB f32 scores
  unsigned short* pbuf = (unsigned short*)sc;   // bf16 [16][PBS] overlay (33,280 B), used after
  const int bh = blockIdx.x, b = bh >> 3, h = bh & 7;
  const int q0 = blockIdx.y * 16;
  const int wave = threadIdx.x >> 6, lane = threadIdx.x & 63;
  const int l15 = lane & 15, lq = lane >> 4;
  const unsigned short* Q  = qh + (size_t)bh * cT * cDK;
  const unsigned short* Kp = kh + (size_t)bh * cT * cDK;
  const unsigned short* Pt = pproj + (size_t)h * cP * cDK;

  const short8 qf0 = ld8(Q + (size_t)(q0 + l15) * cDK + lq * 8);
  const short8 qf1 = ld8(Q + (size_t)(q0 + l15) * cDK + 32 + lq * 8);

  // ---- phase 1: ac = Q K^T -> LDS (2-way banks via SWZ) ----
  for (int jt = wave; jt < 64; jt += 4){
    const short8 kf0 = ld8(Kp + (size_t)(jt * 16 + l15) * cDK + lq * 8);
    const short8 kf1 = ld8(Kp + (size_t)(jt * 16 + l15) * cDK + 32 + lq * 8);
    floatx4 acc = (floatx4){0.f, 0.f, 0.f, 0.f};
    acc = MFMA16(qf0, kf0, acc);
    acc = MFMA16(qf1, kf1, acc);
    const int jb = jt * 16 + l15;
    #pragma unroll
    for (int r = 0; r < 4; r++){
      const int i = lq * 4 + r;
      sc[i * cT + (jb ^ (lq << 3))] = acc[r];   // SWZ(i,jb), i>>2 == lq
    }
  }
  __syncthreads();

  // ---- phase 2: bd window GEMM, diagonal scatter-add  j = c - 15 + i ----
  const int w0 = (cT - 1) - q0 - 15;
  for (int ct = wave; ct < 65; ct += 4){
    const int c = ct * 16 + l15;
    int prow = w0 + c; if (prow > cP - 1) prow = cP - 1;  // clamped rows -> j>=1024, dropped
    const short8 pf0 = ld8(Pt + (size_t)prow * cDK + lq * 8);
    const short8 pf1 = ld8(Pt + (size_t)prow * cDK + 32 + lq * 8);
    floatx4 acc = (floatx4){0.f, 0.f, 0.f, 0.f};
    acc = MFMA16(qf0, pf0, acc);
    acc = MFMA16(qf1, pf1, acc);
    #pragma unroll
    for (int r = 0; r < 4; r++){
      const int i = lq * 4 + r;
      const int j = c - 15 + i;
      if (j >= 0 && j < cT) sc[i * cT + SWZ(i, j)] += acc[r];
    }
  }
  __syncthreads();

  // ---- phase 3: masked softmax, 4 passes (read | barrier | write) ----
  // pass p: wave w handles row i = 4p + w. pb writes of pass p only touch
  // sc rows < 4(p+1), which are fully consumed by the end of pass p's reads.
  const float* ub = ubias + (size_t)bh * cT;
  const float* vb = vbias + (size_t)h * cP;
  for (int p = 0; p < 4; p++){
    const int i = p * 4 + wave;
    const int qrow = q0 + i;
    const unsigned int* bmr = bm + ((size_t)b * cT + qrow) * 32;
    float vals[16];
    float mx = -INFINITY;
    #pragma unroll
    for (int ii = 0; ii < 16; ii++){
      const int j = lane + ii * 64;
      float s = sc[i * cT + SWZ(i, j)] + ub[j] + vb[j + (cT - 1) - qrow];
      const unsigned int mw = bmr[ii * 2 + (lane >> 5)];
      if (((mw >> (lane & 31)) & 1u) == 0u) s = -INFINITY;
      vals[ii] = s;
      mx = fmaxf(mx, s);
    }
    #pragma unroll
    for (int o = 32; o; o >>= 1) mx = fmaxf(mx, __shfl_xor(mx, o));
    float sum = 0.f;
    #pragma unroll
    for (int ii = 0; ii < 16; ii++){
      const float e = (vals[ii] == -INFINITY) ? 0.f : __expf(vals[ii] - mx);
      vals[ii] = e; sum += e;
    }
    #pragma unroll
    for (int o = 32; o; o >>= 1) sum += __shfl_xor(sum, o);
    const float ri = sum > 0.f ? 1.f / sum : 0.f;
    __syncthreads();            // all reads of rows 4p..4p+3 complete
    float* arow = attn_out + ((size_t)bh * cT + qrow) * cT;
    #pragma unroll
    for (int ii = 0; ii < 16; ii++){
      const int j = lane + ii * 64;
      const float pr = vals[ii] * ri;
      __builtin_nontemporal_store(pr, arow + j);   // don't evict L2-resident K/V/P
      pbuf[i * PBS + j] = f2bf(pr);                // 2-way banks (pairs share a word)
    }
  }
  __syncthreads();

  // ---- phase 4: O = P V via ds_read_b128 bf16 fragments ----
  const unsigned short* V = vt + (size_t)bh * cDK * cT;
  const int d0 = wave * 16;
  floatx4 acc = (floatx4){0.f, 0.f, 0.f, 0.f};
  for (int ks = 0; ks < 32; ks++){
    const int j0 = ks * 32;
    const short8 vf = ld8(V + (size_t)(d0 + l15) * cT + j0 + lq * 8);
    const short8 af = ld8(pbuf + l15 * PBS + j0 + lq * 8);
    acc = MFMA16(af, vf, acc);
  }
  #pragma unroll
  for (int r = 0; r < 4; r++){
    const int i = lq * 4 + r;
    out_h[((size_t)b * cT + q0 + i) * cD + h * cDK + d0 + l15] = f2bf(acc[r]);
  }
}

// ---------------- host launcher ----------------
extern "C" void kernel_launch(void* const* d_in, const int* in_sizes, int n_in,
                              void* d_out, int out_size, void* d_ws, size_t ws_size,
                              hipStream_t stream)
{
  const float* q    = (const float*)d_in[0];
  const float* k    = (const float*)d_in[1];
  const float* v    = (const float*)d_in[2];
  const float* pe   = (const float*)d_in[3];
  const int*   mask = (const int*)d_in[4];
  const float* lnqg = (const float*)d_in[5];
  const float* lnqb = (const float*)d_in[6];
  const float* lnkg = (const float*)d_in[7];
  const float* lnkb = (const float*)d_in[8];
  const float* lnvg = (const float*)d_in[9];
  const float* lnvb = (const float*)d_in[10];
  const float* wq   = (const float*)d_in[11];
  const float* wk   = (const float*)d_in[12];
  const float* wv   = (const float*)d_in[13];
  const float* wpos = (const float*)d_in[14];
  const float* wfc  = (const float*)d_in[15];
  const float* pbu  = (const float*)d_in[16];
  const float* pbv  = (const float*)d_in[17];

  float* out_f  = (float*)d_out;                       // [8,1024,512] f32
  float* attn_f = out_f + (size_t)8 * 1024 * 512;      // [8,8,1024,1024] f32, 268 MB

  // --- scratch dead before attn_kernel lives inside the attn output region ---
  unsigned char* scr = (unsigned char*)attn_f;
  size_t soff = 0;
  auto salloc = [&](size_t bytes){ void* p = scr + soff; soff += (bytes + 255) & ~(size_t)255; return p; };
  unsigned short* qn   = (unsigned short*)salloc((size_t)8192 * 512 * 2);  // qn,kn,vn consecutive
  unsigned short* kn   = (unsigned short*)salloc((size_t)8192 * 512 * 2);
  unsigned short* vn   = (unsigned short*)salloc((size_t)8192 * 512 * 2);
  unsigned short* pe_b = (unsigned short*)salloc((size_t)2047 * 512 * 2);
  (void)kn; (void)vn;

  // --- workspace: buffers that live across / after attn_kernel (~46 MB) ---
  unsigned char* ws = (unsigned char*)d_ws;
  size_t off = 0;
  auto alloc = [&](size_t bytes){ void* p = ws + off; off += (bytes + 255) & ~(size_t)255; return p; };
  unsigned short* w5_b = (unsigned short*)alloc(5 * 512 * 512 * 2);        // wq,wk,wv,wpos,wfc
  unsigned short* qhb  = (unsigned short*)alloc((size_t)8192 * 512 * 2);   // qhb,khb,vhb consecutive
  unsigned short* khb  = (unsigned short*)alloc((size_t)8192 * 512 * 2);
  unsigned short* vhb  = (unsigned short*)alloc((size_t)8192 * 512 * 2);
  unsigned short* vtb  = (unsigned short*)alloc((size_t)8192 * 512 * 2);   // [B,H,64,T]
  unsigned short* ppb  = (unsigned short*)alloc((size_t)8 * 2047 * 64 * 2);// [H,P,64]
  float*          ub   = (float*)alloc((size_t)8 * 8 * 1024 * 4);          // [B,H,T]
  float*          vbias= (float*)alloc((size_t)8 * 2047 * 4);              // [H,P]
  unsigned short* ohb  = (unsigned short*)alloc((size_t)8192 * 512 * 2);   // [B,T,512]
  unsigned int*   bmask= (unsigned int*)alloc((size_t)8192 * 32 * 4);      // [B,T,32]
  (void)ws_size; (void)n_in; (void)in_sizes; (void)out_size;

  Ptr5 c5; c5.p[0] = wq; c5.p[1] = wk; c5.p[2] = wv; c5.p[3] = wpos; c5.p[4] = wfc;
  cast5_kernel<<<5120, 256, 0, stream>>>(c5, w5_b);
  cast1_kernel<<<4094, 256, 0, stream>>>(pe, pe_b, 2047 * 512);
  maskbits_kernel<<<2048, 256, 0, stream>>>(mask, bmask);

  LN3 l3;
  l3.x[0] = q; l3.x[1] = k; l3.x[2] = v;
  l3.g[0] = lnqg; l3.g[1] = lnkg; l3.g[2] = lnvg;
  l3.b[0] = lnqb; l3.b[1] = lnkb; l3.b[2] = lnvb;
  l3.y[0] = qn; l3.y[1] = kn; l3.y[2] = vn;
  ln3_kernel<<<dim3(8192, 3), 256, 0, stream>>>(l3);

  // fused QKV projections (z=0:q scaled by 1/8, z=1:k, z=2:v)
  gemm512_kernel<<<dim3(4, 64, 3), 256, 0, stream>>>(qn, w5_b, 8192, 0, 0.125f,
                                                     qhb, nullptr, nullptr);
  gemm512_kernel<<<dim3(4, 16, 1), 256, 0, stream>>>(pe_b, w5_b + 3 * 262144, 2047, 1, 1.0f,
                                                     ppb, nullptr, nullptr);

  transpose_v_kernel<<<dim3(64, 16), 256, 0, stream>>>(vhb, vtb);

  dot_bias_kernel<<<16384, 256, 0, stream>>>(khb, pbu, ub, 65536, 1024, 0.125f);
  dot_bias_kernel<<<4094, 256, 0, stream>>>(ppb, pbv, vbias, 16376, 2047, 0.125f);

  attn_kernel<<<dim3(64, 64), 256, 0, stream>>>(qhb, khb, vtb, ppb, ub, vbias,
                                                bmask, attn_f, ohb);

  gemm512_kernel<<<dim3(4, 64, 1), 256, 0, stream>>>(ohb, w5_b + 4 * 262144, 8192, 2, 1.0f,
                                                     nullptr, out_f, q);
}